// Round 5
// baseline (1513.672 us; speedup 1.0000x reference)
//
#include <hip/hip_runtime.h>
#include <hip/hip_bf16.h>

// ---- problem constants (fixed by setup_inputs) ----
#define BB 32
#define HD 32
#define N0 16384
#define C0 3
#define E0v 131072
#define N1 4096
#define E1v 32768
#define N2 1024
#define E2v 8192
#define N3 128
#define E3v 1024
#define FDIM 4096
#define LDIM 128
#define NT (N0 + N1 + N2 + N3)     // 21632
#define ET (E0v + E1v + E2v + E3v) // 173056
#define EPSBN 1e-5f
#define KC 64                       // big-GEMM split-K chunks (K=4096/64)
#define KC9 64                      // gemm9 split-K chunks
// All tensors are float32 (established round 4).
// R3/R4 lesson: grid-barrier fusion of levels 2-4 starved TLP (2 waves/CU,
// 220 GB/s latency-bound) — separate kernels with big grids win. Reverted.

// ---------------- CSR build (all 4 levels in one pass) ----------------
__global__ void k_count(const int* __restrict__ e0, const int* __restrict__ e1,
                        const int* __restrict__ e2, const int* __restrict__ e3,
                        int* __restrict__ deg) {
    int e = blockIdx.x * 256 + threadIdx.x;
    if (e >= ET) return;
    const int* p; int idx, nb;
    if (e < E0v)                     { p = e0; idx = e; nb = 0; }
    else if (e < E0v + E1v)          { p = e1; idx = e - E0v; nb = N0; }
    else if (e < E0v + E1v + E2v)    { p = e2; idx = e - E0v - E1v; nb = N0 + N1; }
    else                             { p = e3; idx = e - E0v - E1v - E2v; nb = N0 + N1 + N2; }
    atomicAdd(&deg[nb + p[idx]], 1);
}

__global__ void __launch_bounds__(1024) k_scan(const int* __restrict__ deg,
                                               int* __restrict__ offs, int* __restrict__ cur) {
    __shared__ int ss[1024];
    int t = threadIdx.x, base = t * 22;
    int loc[22]; int s = 0;
#pragma unroll
    for (int i = 0; i < 22; i++) {
        int idx = base + i;
        int v = (idx < NT) ? deg[idx] : 0;
        loc[i] = s; s += v;
    }
    ss[t] = s;
    __syncthreads();
    int run = s;
    for (int o = 1; o < 1024; o <<= 1) {
        int y = (t >= o) ? ss[t - o] : 0;
        __syncthreads();
        run += y; ss[t] = run;
        __syncthreads();
    }
    int excl = run - s;
#pragma unroll
    for (int i = 0; i < 22; i++) {
        int idx = base + i;
        if (idx < NT) { int v = excl + loc[i]; offs[idx] = v; cur[idx] = v; }
    }
    if (t == 0) offs[NT] = ET;
}

// packed edge: .x = level-local col, .y = bitcast weight
__global__ void k_scatter(const int* __restrict__ e0, const int* __restrict__ e1,
                          const int* __restrict__ e2, const int* __restrict__ e3,
                          const int* __restrict__ deg, int* __restrict__ cur,
                          int2* __restrict__ cpk) {
    int e = blockIdx.x * 256 + threadIdx.x;
    if (e >= ET) return;
    const int* p; int idx, nb, El;
    if (e < E0v)                  { p = e0; idx = e; nb = 0; El = E0v; }
    else if (e < E0v + E1v)       { p = e1; idx = e - E0v; nb = N0; El = E1v; }
    else if (e < E0v + E1v + E2v) { p = e2; idx = e - E0v - E1v; nb = N0 + N1; El = E2v; }
    else                          { p = e3; idx = e - E0v - E1v - E2v; nb = N0 + N1 + N2; El = E3v; }
    int r = p[idx], c = p[El + idx];
    int pos = atomicAdd(&cur[nb + r], 1);
    int dr = deg[nb + r], dc = deg[nb + c];
    float w = 0.f;
    if (dr > 0 && dc > 0)
        w = -(1.f / sqrtf((float)dr)) * (1.f / sqrtf((float)dc));
    cpk[pos] = make_int2(c, __float_as_int(w));
}

// ---------------- transpose x [B][N0][3] -> xt [N0][96] (q = b*3+c) ----------------
__global__ void k_transpose(const float* __restrict__ x, float* __restrict__ xt) {
    __shared__ float t0[32][33], t1[32][33], t2[32][33];
    int tx = threadIdx.x, ty = threadIdx.y;      // (32, 8)
    int n0 = blockIdx.x * 32;
#pragma unroll
    for (int i = 0; i < 4; i++) {
        int b = ty * 4 + i;
        size_t base = ((size_t)b * N0 + n0 + tx) * 3;
        t0[tx][b] = x[base];
        t1[tx][b] = x[base + 1];
        t2[tx][b] = x[base + 2];
    }
    __syncthreads();
#pragma unroll
    for (int i = 0; i < 4; i++) {
        int nl = ty * 4 + i;
        size_t o = (size_t)(n0 + nl) * 96 + tx * 3;
        xt[o]     = t0[nl][tx];
        xt[o + 1] = t1[nl][tx];
        xt[o + 2] = t2[nl][tx];
    }
}

// ---------------- level-0 prop (float4, packed edges) ----------------
__global__ void k_prop0(const float* __restrict__ xt, float* __restrict__ T1t,
                        const int* __restrict__ offs, const int2* __restrict__ cpk) {
    int idx = blockIdx.x * 256 + threadIdx.x;  // over N0*24 float4 slots
    int n = (unsigned)idx / 24u;
    int q = (idx - n * 24) * 4;
    int s = offs[n], e = offs[n + 1];
    float4 acc = { 0.f, 0.f, 0.f, 0.f };
    for (int k = s; k < e; k++) {
        int2 ew = cpk[k];
        float w = __int_as_float(ew.y);
        float4 v = *(const float4*)&xt[(size_t)ew.x * 96 + q];
        acc.x += w * v.x; acc.y += w * v.y; acc.z += w * v.z; acc.w += w * v.w;
    }
    *(float4*)&T1t[(size_t)n * 96 + q] = acc;
}

// ---------------- level-0 combine ----------------
__global__ void k_comb0(const float* __restrict__ xt, const float* __restrict__ T1t,
                        const int* __restrict__ offs, const int2* __restrict__ cpk,
                        const int* __restrict__ pool,
                        const float* __restrict__ W, const float* __restrict__ bias,
                        float* __restrict__ Yout) {
    __shared__ __align__(16) float s0[96], s1[96], s2[96];
    __shared__ float sw[288], sb[32];
    int t = threadIdx.x;
    int j = blockIdx.x;
    int n = pool[j];
    size_t nb = (size_t)n * 96;
    if (t < 24) {
        *(float4*)&s0[t * 4] = *(const float4*)&xt[nb + t * 4];
        *(float4*)&s1[t * 4] = *(const float4*)&T1t[nb + t * 4];
        int s = offs[n], e = offs[n + 1];
        float4 ga = { 0.f, 0.f, 0.f, 0.f };
        for (int k = s; k < e; k++) {
            int2 ew = cpk[k];
            float w = __int_as_float(ew.y);
            float4 v = *(const float4*)&T1t[(size_t)ew.x * 96 + t * 4];
            ga.x += w * v.x; ga.y += w * v.y; ga.z += w * v.z; ga.w += w * v.w;
        }
        *(float4*)&s2[t * 4] = ga;
    }
    for (int i = t; i < 288; i += 64) sw[i] = W[i];
    if (t < 32) sb[t] = bias[t];
    __syncthreads();

    int f0 = (t & 7) * 4;
    int b0 = (t >> 3) * 4;
    float acc[4][4];
#pragma unroll
    for (int bi = 0; bi < 4; bi++)
#pragma unroll
        for (int fi = 0; fi < 4; fi++) acc[bi][fi] = sb[f0 + fi];
#pragma unroll
    for (int c = 0; c < 3; c++) {
        float4 w0 = *(float4*)&sw[(0 * 3 + c) * 32 + f0];
        float4 w1 = *(float4*)&sw[(1 * 3 + c) * 32 + f0];
        float4 w2 = *(float4*)&sw[(2 * 3 + c) * 32 + f0];
#pragma unroll
        for (int bi = 0; bi < 4; bi++) {
            int b = b0 + bi;
            float x0 = s0[b * 3 + c], x1 = s1[b * 3 + c];
            float x2 = 2.f * s2[b * 3 + c] - x0;
            acc[bi][0] += x0 * w0.x + x1 * w1.x + x2 * w2.x;
            acc[bi][1] += x0 * w0.y + x1 * w1.y + x2 * w2.y;
            acc[bi][2] += x0 * w0.z + x1 * w1.z + x2 * w2.z;
            acc[bi][3] += x0 * w0.w + x1 * w1.w + x2 * w2.w;
        }
    }
#pragma unroll
    for (int bi = 0; bi < 4; bi++) {
        float4 v = { acc[bi][0], acc[bi][1], acc[bi][2], acc[bi][3] };
        *(float4*)&Yout[(size_t)j * 1024 + (b0 + bi) * 32 + f0] = v;
    }
}

// ---------------- levels 1-4 prop: block-per-node, float4 per thread ----------------
__global__ void k_propC(const float* __restrict__ Yin, float* __restrict__ T1,
                        const int* __restrict__ offs, const int2* __restrict__ cpk) {
    int n = blockIdx.x;
    int q = threadIdx.x * 4;
    int s = offs[n], e = offs[n + 1];
    float4 acc = { 0.f, 0.f, 0.f, 0.f };
    for (int k = s; k < e; k++) {
        int2 ew = cpk[k];
        float w = __int_as_float(ew.y);
        float4 v = *(const float4*)&Yin[((size_t)ew.x << 10) + q];
        acc.x += w * v.x; acc.y += w * v.y; acc.z += w * v.z; acc.w += w * v.w;
    }
    *(float4*)&T1[((size_t)n << 10) + q] = acc;
}

// ---------------- levels 1-4 combine (64 threads) ----------------
__global__ void k_combC(const float* __restrict__ Yin, const float* __restrict__ T1,
                        const int* __restrict__ offs, const int2* __restrict__ cpk,
                        const int* __restrict__ pool,
                        const float* __restrict__ W, const float* __restrict__ bias,
                        float* __restrict__ Yout, int doTanh, int bMajor) {
    __shared__ float s0[32 * 33], s1[32 * 33], s2[32 * 33], sw[3072], sb[32];
    int t = threadIdx.x;
    int j = blockIdx.x;
    int n = pool ? pool[j] : j;
    size_t nb = (size_t)n << 10;
#pragma unroll
    for (int i = 0; i < 4; i++) {
        int q = t * 4 + i * 256;
        float4 v0 = *(const float4*)&Yin[nb + q];
        float4 v1 = *(const float4*)&T1[nb + q];
        int li = (q >> 5) * 33 + (q & 31);
        s0[li] = v0.x; s0[li + 1] = v0.y; s0[li + 2] = v0.z; s0[li + 3] = v0.w;
        s1[li] = v1.x; s1[li + 1] = v1.y; s1[li + 2] = v1.z; s1[li + 3] = v1.w;
    }
    {
        int s = offs[n], e = offs[n + 1];
        float4 ga[4];
#pragma unroll
        for (int i = 0; i < 4; i++) ga[i] = make_float4(0.f, 0.f, 0.f, 0.f);
        for (int k = s; k < e; k++) {
            int2 ew = cpk[k];
            float w = __int_as_float(ew.y);
            const float* bp = T1 + ((size_t)ew.x << 10);
#pragma unroll
            for (int i = 0; i < 4; i++) {
                float4 v = *(const float4*)&bp[t * 4 + i * 256];
                ga[i].x += w * v.x; ga[i].y += w * v.y;
                ga[i].z += w * v.z; ga[i].w += w * v.w;
            }
        }
#pragma unroll
        for (int i = 0; i < 4; i++) {
            int q = t * 4 + i * 256;
            int li = (q >> 5) * 33 + (q & 31);
            s2[li] = ga[i].x; s2[li + 1] = ga[i].y; s2[li + 2] = ga[i].z; s2[li + 3] = ga[i].w;
        }
    }
    for (int i = t; i < 768; i += 64) ((float4*)sw)[i] = ((const float4*)W)[i];
    if (t < 32) sb[t] = bias[t];
    __syncthreads();

    int f0 = (t & 7) * 4;
    int b0 = (t >> 3) * 4;
    float acc[4][4];
#pragma unroll
    for (int bi = 0; bi < 4; bi++)
#pragma unroll
        for (int fi = 0; fi < 4; fi++) acc[bi][fi] = sb[f0 + fi];
    for (int c = 0; c < 32; c++) {
        float4 w0 = *(float4*)&sw[c * 32 + f0];
        float4 w1 = *(float4*)&sw[1024 + c * 32 + f0];
        float4 w2 = *(float4*)&sw[2048 + c * 32 + f0];
#pragma unroll
        for (int bi = 0; bi < 4; bi++) {
            int li = (b0 + bi) * 33 + c;
            float x0 = s0[li], x1 = s1[li];
            float x2 = 2.f * s2[li] - x0;
            acc[bi][0] += x0 * w0.x + x1 * w1.x + x2 * w2.x;
            acc[bi][1] += x0 * w0.y + x1 * w1.y + x2 * w2.y;
            acc[bi][2] += x0 * w0.z + x1 * w1.z + x2 * w2.z;
            acc[bi][3] += x0 * w0.w + x1 * w1.w + x2 * w2.w;
        }
    }
    if (doTanh) {
#pragma unroll
        for (int bi = 0; bi < 4; bi++)
#pragma unroll
            for (int fi = 0; fi < 4; fi++) acc[bi][fi] = tanhf(acc[bi][fi]);
    }
#pragma unroll
    for (int bi = 0; bi < 4; bi++) {
        float4 v = { acc[bi][0], acc[bi][1], acc[bi][2], acc[bi][3] };
        if (bMajor)
            *(float4*)&Yout[(size_t)(b0 + bi) * FDIM + j * 32 + f0] = v;
        else
            *(float4*)&Yout[((size_t)j << 10) + (b0 + bi) * 32 + f0] = v;
    }
}

// ---------------- MLP ----------------
// Z[32][4096] @ W[4096][4096] -> Hp[kc][32][4096] partials.
// grid (32, KC=64) = 2048 blocks -> 8 blocks/CU, 32 waves/CU (full occupancy).
// 128-col f-tiles keep acc+w+z ~56 VGPR -> under the 64-VGPR occupancy cliff.
// TLP (8 waves/SIMD) hides W-load latency; no software prefetch needed.
__global__ void __launch_bounds__(256, 8) k_gemm(const float* __restrict__ Z,
                                                 const float* __restrict__ W,
                                                 float* __restrict__ Hp) {
    int t = threadIdx.x; int bx = blockIdx.x; int kc = blockIdx.y; int kb = kc * 64;
    __shared__ float zs[32][64];
    for (int i = t; i < 512; i += 256) {
        int fl = i * 4; int b = fl >> 6; int k = fl & 63;
        *(float4*)&zs[b][k] = *(const float4*)&Z[(size_t)b * 4096 + kb + k];
    }
    __syncthreads();
    int ft = t & 31, bt = t >> 5;          // 32 f-threads (4 cols) x 8 b-groups (4 rows)
    int f0 = bx * 128 + ft * 4;
    int b0 = bt * 4;
    const float* Wp = W + (size_t)kb * 4096 + f0;
    float acc[4][4];
#pragma unroll
    for (int bi = 0; bi < 4; bi++)
#pragma unroll
        for (int fi = 0; fi < 4; fi++) acc[bi][fi] = 0.f;
    for (int k4 = 0; k4 < 16; k4++) {
        float4 w[4];
#pragma unroll
        for (int j = 0; j < 4; j++)
            w[j] = *(const float4*)&Wp[(size_t)(k4 * 4 + j) * 4096];
        float4 z[4];
#pragma unroll
        for (int bi = 0; bi < 4; bi++)
            z[bi] = *(const float4*)&zs[b0 + bi][k4 * 4];
#pragma unroll
        for (int bi = 0; bi < 4; bi++) {
            acc[bi][0] += z[bi].x * w[0].x + z[bi].y * w[1].x + z[bi].z * w[2].x + z[bi].w * w[3].x;
            acc[bi][1] += z[bi].x * w[0].y + z[bi].y * w[1].y + z[bi].z * w[2].y + z[bi].w * w[3].y;
            acc[bi][2] += z[bi].x * w[0].z + z[bi].y * w[1].z + z[bi].z * w[2].z + z[bi].w * w[3].z;
            acc[bi][3] += z[bi].x * w[0].w + z[bi].y * w[1].w + z[bi].z * w[2].w + z[bi].w * w[3].w;
        }
    }
    float* o = Hp + (size_t)kc * 32 * 4096;
#pragma unroll
    for (int bi = 0; bi < 4; bi++) {
        float4 v = { acc[bi][0], acc[bi][1], acc[bi][2], acc[bi][3] };
        *(float4*)&o[(size_t)(b0 + bi) * 4096 + f0] = v;
    }
}

// reduce KC partials + BN(batch) + affine + relu. grid 128, block 256 = 32f x 8bq(4b).
__global__ void k_bnrelu(const float* __restrict__ Hp, const float* __restrict__ g,
                         const float* __restrict__ be, float* __restrict__ Zo) {
    __shared__ float sA[8][33], sB[8][33], sm[32], si[32];
    int t = threadIdx.x; int fq = t & 31; int bq = t >> 5;
    int f = blockIdx.x * 32 + fq;
    float v[4];
#pragma unroll
    for (int i = 0; i < 4; i++) v[i] = 0.f;
    for (int p = 0; p < KC; p++) {
        const float* hp = Hp + (size_t)p * 32 * 4096;
#pragma unroll
        for (int i = 0; i < 4; i++) v[i] += hp[(size_t)(bq * 4 + i) * 4096 + f];
    }
    float a = 0.f, q = 0.f;
#pragma unroll
    for (int i = 0; i < 4; i++) { a += v[i]; q += v[i] * v[i]; }
    sA[bq][fq] = a; sB[bq][fq] = q;
    __syncthreads();
    if (t < 32) {
        float m = 0.f, qq = 0.f;
#pragma unroll
        for (int i = 0; i < 8; i++) { m += sA[i][t]; qq += sB[i][t]; }
        m *= (1.f / 32.f);
        qq = qq * (1.f / 32.f) - m * m;
        sm[t] = m; si[t] = rsqrtf(fmaxf(qq, 0.f) + EPSBN);
    }
    __syncthreads();
    float m = sm[fq], inv = si[fq], gg = g[f], bb = be[f];
#pragma unroll
    for (int i = 0; i < 4; i++) {
        float o = (v[i] - m) * inv * gg + bb;
        Zo[(size_t)(bq * 4 + i) * 4096 + f] = fmaxf(o, 0.f);
    }
}

// Z[32][4096] @ W9[4096][128] -> Mp[kc][32][128]. grid KC9, block 128 = 32f(4) x 4bq(8).
__global__ void __launch_bounds__(128, 2) k_gemm9(const float* __restrict__ Z,
                                                  const float* __restrict__ W9,
                                                  float* __restrict__ Mp) {
    int t = threadIdx.x; int kc = blockIdx.x; int kb = kc * 64;
    __shared__ float zs[32][64];
    for (int i = t; i < 512; i += 128) {
        int fl = i * 4; int b = fl >> 6; int k = fl & 63;
        *(float4*)&zs[b][k] = *(const float4*)&Z[(size_t)b * 4096 + kb + k];
    }
    __syncthreads();
    int ft = t & 31, bt = t >> 5;
    int f0 = ft * 4;
    int b0 = bt * 8;
    const float* Wp = W9 + (size_t)kb * 128 + f0;
    float acc[8][4];
#pragma unroll
    for (int bi = 0; bi < 8; bi++)
#pragma unroll
        for (int fi = 0; fi < 4; fi++) acc[bi][fi] = 0.f;
    for (int k4 = 0; k4 < 16; k4++) {
        float4 w[4];
#pragma unroll
        for (int j = 0; j < 4; j++)
            w[j] = *(const float4*)&Wp[(size_t)(k4 * 4 + j) * 128];
        float4 z[8];
#pragma unroll
        for (int bi = 0; bi < 8; bi++)
            z[bi] = *(const float4*)&zs[b0 + bi][k4 * 4];
#pragma unroll
        for (int bi = 0; bi < 8; bi++) {
            acc[bi][0] += z[bi].x * w[0].x + z[bi].y * w[1].x + z[bi].z * w[2].x + z[bi].w * w[3].x;
            acc[bi][1] += z[bi].x * w[0].y + z[bi].y * w[1].y + z[bi].z * w[2].y + z[bi].w * w[3].y;
            acc[bi][2] += z[bi].x * w[0].z + z[bi].y * w[1].z + z[bi].z * w[2].z + z[bi].w * w[3].z;
            acc[bi][3] += z[bi].x * w[0].w + z[bi].y * w[1].w + z[bi].z * w[2].w + z[bi].w * w[3].w;
        }
    }
    float* o = Mp + (size_t)kc * 32 * 128;
#pragma unroll
    for (int bi = 0; bi < 8; bi++) {
        float4 v = { acc[bi][0], acc[bi][1], acc[bi][2], acc[bi][3] };
        *(float4*)&o[(b0 + bi) * 128 + f0] = v;
    }
}

__global__ void k_red9(const float* __restrict__ Mp, float* __restrict__ Mu) {
    int idx = blockIdx.x * 256 + threadIdx.x;
    if (idx >= 4096) return;
    float a = 0.f;
    for (int p = 0; p < KC9; p++) a += Mp[(size_t)p * 4096 + idx];
    Mu[idx] = a;
}

__global__ void k_bnfinal(const float* __restrict__ Mu, float* __restrict__ out) {
    int f = threadIdx.x;
    float v[32], s = 0.f;
#pragma unroll
    for (int b = 0; b < 32; b++) { v[b] = Mu[b * 128 + f]; s += v[b]; }
    float m = s * (1.f / 32.f), q = 0.f;
#pragma unroll
    for (int b = 0; b < 32; b++) { float d = v[b] - m; q += d * d; }
    float inv = rsqrtf(q * (1.f / 32.f) + EPSBN);
#pragma unroll
    for (int b = 0; b < 32; b++) out[b * 128 + f] = (v[b] - m) * inv;
}

// ---------------- host ----------------
extern "C" void kernel_launch(void* const* d_in, const int* in_sizes, int n_in,
                              void* d_out, int out_size, void* d_ws, size_t ws_size,
                              hipStream_t stream) {
    const float* x  = (const float*)d_in[0];
    const int* e0 = (const int*)d_in[1];
    const int* e1 = (const int*)d_in[2];
    const int* e2 = (const int*)d_in[3];
    const int* e3 = (const int*)d_in[4];
    const int* l0 = (const int*)d_in[5];
    const int* l1 = (const int*)d_in[6];
    const int* l2 = (const int*)d_in[7];
    const float* Wc1 = (const float*)d_in[8];
    const float* b1  = (const float*)d_in[9];
    const float* Wc2 = (const float*)d_in[10];
    const float* b2  = (const float*)d_in[11];
    const float* Wc3 = (const float*)d_in[12];
    const float* b3  = (const float*)d_in[13];
    const float* Wc4 = (const float*)d_in[14];
    const float* b4  = (const float*)d_in[15];
    const float* Wc5 = (const float*)d_in[16];
    const float* b5  = (const float*)d_in[17];
    const float* W6  = (const float*)d_in[18];
    const float* g6  = (const float*)d_in[20];
    const float* be6 = (const float*)d_in[21];
    const float* W7  = (const float*)d_in[22];
    const float* g7  = (const float*)d_in[24];
    const float* be7 = (const float*)d_in[25];
    const float* W8  = (const float*)d_in[26];
    const float* g8  = (const float*)d_in[28];
    const float* be8 = (const float*)d_in[29];
    const float* W9  = (const float*)d_in[30];
    float* out = (float*)d_out;

    char* p = (char*)d_ws;
    size_t o = 0;
    auto carve = [&](size_t bytes) {
        void* r = (void*)(p + o);
        o += (bytes + 255) & ~(size_t)255;
        return r;
    };
    // graph-phase buffers (dead by MLP time; Hp aliases this span)
    float* xt  = (float*)carve((size_t)N0 * 96 * 4);       // 6.3 MB
    float* T1t = (float*)carve((size_t)N0 * 96 * 4);       // 6.3 MB
    float* Y1  = (float*)carve((size_t)N1 * 1024 * 4);     // 16.8 MB
    float* T1c = (float*)carve((size_t)N1 * 1024 * 4);     // 16.8 MB (reused all levels)
    float* Y2  = (float*)carve((size_t)N2 * 1024 * 4);     // 4.2 MB
    float* Y3  = (float*)carve((size_t)N3 * 1024 * 4);     // 0.5 MB
    float* Y4  = (float*)carve((size_t)N3 * 1024 * 4);     // 0.5 MB
    float* Zb0 = (float*)carve((size_t)BB * FDIM * 4);
    float* Zb1 = (float*)carve((size_t)BB * FDIM * 4);
    float* Mp  = (float*)carve((size_t)KC9 * BB * LDIM * 4);
    float* Mu  = (float*)carve((size_t)BB * LDIM * 4);
    int* deg  = (int*)carve(NT * sizeof(int));
    int* offs = (int*)carve((NT + 1) * sizeof(int));
    int* cur  = (int*)carve(NT * sizeof(int));
    int2* cpk = (int2*)carve(ET * sizeof(int2));
    float* Hp = xt;  // alias: KC*32*4096*4 = 33.6 MB fits in xt..T1c span (46.2 MB)
    (void)ws_size;

    // CSR for all 4 levels
    hipMemsetAsync(deg, 0, NT * sizeof(int), stream);
    k_count<<<(ET + 255) / 256, 256, 0, stream>>>(e0, e1, e2, e3, deg);
    k_scan<<<1, 1024, 0, stream>>>(deg, offs, cur);
    k_scatter<<<(ET + 255) / 256, 256, 0, stream>>>(e0, e1, e2, e3, deg, cur, cpk);

    const int* off0 = offs;
    const int* off1 = offs + N0;
    const int* off2 = offs + N0 + N1;
    const int* off3 = offs + N0 + N1 + N2;

    // node-major transpose of x
    k_transpose<<<N0 / 32, dim3(32, 8), 0, stream>>>(x, xt);

    // level 0
    k_prop0<<<(N0 * 24) / 256, 256, 0, stream>>>(xt, T1t, off0, cpk);
    k_comb0<<<N1, 64, 0, stream>>>(xt, T1t, off0, cpk, l0, Wc1, b1, Y1);
    // level 1
    k_propC<<<N1, 256, 0, stream>>>(Y1, T1c, off1, cpk);
    k_combC<<<N2, 64, 0, stream>>>(Y1, T1c, off1, cpk, l1, Wc2, b2, Y2, 1, 0);
    // level 2
    k_propC<<<N2, 256, 0, stream>>>(Y2, T1c, off2, cpk);
    k_combC<<<N3, 64, 0, stream>>>(Y2, T1c, off2, cpk, l2, Wc3, b3, Y3, 1, 0);
    // level 3
    k_propC<<<N3, 256, 0, stream>>>(Y3, T1c, off3, cpk);
    k_combC<<<N3, 64, 0, stream>>>(Y3, T1c, off3, cpk, nullptr, Wc4, b4, Y4, 1, 0);
    // level 4 -> batch-major Z
    k_propC<<<N3, 256, 0, stream>>>(Y4, T1c, off3, cpk);
    k_combC<<<N3, 64, 0, stream>>>(Y4, T1c, off3, cpk, nullptr, Wc5, b5, Zb0, 0, 1);

    // MLP (Hp aliases graph buffers — graph section fully precedes this)
    const float* Ws[3]  = { W6, W7, W8 };
    const float* gs[3]  = { g6, g7, g8 };
    const float* bes[3] = { be6, be7, be8 };
    float* zin = Zb0; float* zout = Zb1;
    for (int l = 0; l < 3; l++) {
        k_gemm<<<dim3(32, KC), 256, 0, stream>>>(zin, Ws[l], Hp);
        k_bnrelu<<<128, 256, 0, stream>>>(Hp, gs[l], bes[l], zout);
        float* tmp = zin; zin = zout; zout = tmp;
    }
    k_gemm9<<<KC9, 128, 0, stream>>>(zin, W9, Mp);
    k_red9<<<16, 256, 0, stream>>>(Mp, Mu);
    k_bnfinal<<<1, 128, 0, stream>>>(Mu, out);
    (void)out_size; (void)n_in; (void)in_sizes;
}

// Round 6
// 485.509 us; speedup vs baseline: 3.1177x; 3.1177x over previous
//
#include <hip/hip_runtime.h>
#include <hip/hip_bf16.h>

// ---- problem constants (fixed by setup_inputs) ----
#define BB 32
#define HD 32
#define N0 16384
#define C0 3
#define E0v 131072
#define N1 4096
#define E1v 32768
#define N2 1024
#define E2v 8192
#define N3 128
#define E3v 1024
#define FDIM 4096
#define LDIM 128
#define NT (N0 + N1 + N2 + N3)     // 21632
#define ET (E0v + E1v + E2v + E3v) // 173056
#define EPSBN 1e-5f
#define KC 64                       // big-GEMM split-K chunks (K=4096/64)
#define KC9 64                      // gemm9 split-K chunks
// All tensors are float32 (established round 4).
// R3/R4 lesson: grid-barrier fusion starved TLP — separate kernels win.
// R5 lesson: 128-col k_gemm tile under launch_bounds(256,8) SPILLED to scratch
// (FETCH 433MB, WRITE 790MB, 6.7x overfetch). Round-2 k_gemm restored:
// 256-col tile, acc[8][4], bounds(256,4), 68 VGPR, no spill, <40us.

// ---------------- CSR build (all 4 levels in one pass) ----------------
__global__ void k_count(const int* __restrict__ e0, const int* __restrict__ e1,
                        const int* __restrict__ e2, const int* __restrict__ e3,
                        int* __restrict__ deg) {
    int e = blockIdx.x * 256 + threadIdx.x;
    if (e >= ET) return;
    const int* p; int idx, nb;
    if (e < E0v)                     { p = e0; idx = e; nb = 0; }
    else if (e < E0v + E1v)          { p = e1; idx = e - E0v; nb = N0; }
    else if (e < E0v + E1v + E2v)    { p = e2; idx = e - E0v - E1v; nb = N0 + N1; }
    else                             { p = e3; idx = e - E0v - E1v - E2v; nb = N0 + N1 + N2; }
    atomicAdd(&deg[nb + p[idx]], 1);
}

__global__ void __launch_bounds__(1024) k_scan(const int* __restrict__ deg,
                                               int* __restrict__ offs, int* __restrict__ cur) {
    __shared__ int ss[1024];
    int t = threadIdx.x, base = t * 22;
    int loc[22]; int s = 0;
#pragma unroll
    for (int i = 0; i < 22; i++) {
        int idx = base + i;
        int v = (idx < NT) ? deg[idx] : 0;
        loc[i] = s; s += v;
    }
    ss[t] = s;
    __syncthreads();
    int run = s;
    for (int o = 1; o < 1024; o <<= 1) {
        int y = (t >= o) ? ss[t - o] : 0;
        __syncthreads();
        run += y; ss[t] = run;
        __syncthreads();
    }
    int excl = run - s;
#pragma unroll
    for (int i = 0; i < 22; i++) {
        int idx = base + i;
        if (idx < NT) { int v = excl + loc[i]; offs[idx] = v; cur[idx] = v; }
    }
    if (t == 0) offs[NT] = ET;
}

// packed edge: .x = level-local col, .y = bitcast weight
__global__ void k_scatter(const int* __restrict__ e0, const int* __restrict__ e1,
                          const int* __restrict__ e2, const int* __restrict__ e3,
                          const int* __restrict__ deg, int* __restrict__ cur,
                          int2* __restrict__ cpk) {
    int e = blockIdx.x * 256 + threadIdx.x;
    if (e >= ET) return;
    const int* p; int idx, nb, El;
    if (e < E0v)                  { p = e0; idx = e; nb = 0; El = E0v; }
    else if (e < E0v + E1v)       { p = e1; idx = e - E0v; nb = N0; El = E1v; }
    else if (e < E0v + E1v + E2v) { p = e2; idx = e - E0v - E1v; nb = N0 + N1; El = E2v; }
    else                          { p = e3; idx = e - E0v - E1v - E2v; nb = N0 + N1 + N2; El = E3v; }
    int r = p[idx], c = p[El + idx];
    int pos = atomicAdd(&cur[nb + r], 1);
    int dr = deg[nb + r], dc = deg[nb + c];
    float w = 0.f;
    if (dr > 0 && dc > 0)
        w = -(1.f / sqrtf((float)dr)) * (1.f / sqrtf((float)dc));
    cpk[pos] = make_int2(c, __float_as_int(w));
}

// ---------------- transpose x [B][N0][3] -> xt [N0][96] (q = b*3+c) ----------------
__global__ void k_transpose(const float* __restrict__ x, float* __restrict__ xt) {
    __shared__ float t0[32][33], t1[32][33], t2[32][33];
    int tx = threadIdx.x, ty = threadIdx.y;      // (32, 8)
    int n0 = blockIdx.x * 32;
#pragma unroll
    for (int i = 0; i < 4; i++) {
        int b = ty * 4 + i;
        size_t base = ((size_t)b * N0 + n0 + tx) * 3;
        t0[tx][b] = x[base];
        t1[tx][b] = x[base + 1];
        t2[tx][b] = x[base + 2];
    }
    __syncthreads();
#pragma unroll
    for (int i = 0; i < 4; i++) {
        int nl = ty * 4 + i;
        size_t o = (size_t)(n0 + nl) * 96 + tx * 3;
        xt[o]     = t0[nl][tx];
        xt[o + 1] = t1[nl][tx];
        xt[o + 2] = t2[nl][tx];
    }
}

// ---------------- level-0 prop (float4, packed edges) ----------------
__global__ void k_prop0(const float* __restrict__ xt, float* __restrict__ T1t,
                        const int* __restrict__ offs, const int2* __restrict__ cpk) {
    int idx = blockIdx.x * 256 + threadIdx.x;  // over N0*24 float4 slots
    int n = (unsigned)idx / 24u;
    int q = (idx - n * 24) * 4;
    int s = offs[n], e = offs[n + 1];
    float4 acc = { 0.f, 0.f, 0.f, 0.f };
    for (int k = s; k < e; k++) {
        int2 ew = cpk[k];
        float w = __int_as_float(ew.y);
        float4 v = *(const float4*)&xt[(size_t)ew.x * 96 + q];
        acc.x += w * v.x; acc.y += w * v.y; acc.z += w * v.z; acc.w += w * v.w;
    }
    *(float4*)&T1t[(size_t)n * 96 + q] = acc;
}

// ---------------- level-0 combine ----------------
__global__ void k_comb0(const float* __restrict__ xt, const float* __restrict__ T1t,
                        const int* __restrict__ offs, const int2* __restrict__ cpk,
                        const int* __restrict__ pool,
                        const float* __restrict__ W, const float* __restrict__ bias,
                        float* __restrict__ Yout) {
    __shared__ __align__(16) float s0[96], s1[96], s2[96];
    __shared__ float sw[288], sb[32];
    int t = threadIdx.x;
    int j = blockIdx.x;
    int n = pool[j];
    size_t nb = (size_t)n * 96;
    if (t < 24) {
        *(float4*)&s0[t * 4] = *(const float4*)&xt[nb + t * 4];
        *(float4*)&s1[t * 4] = *(const float4*)&T1t[nb + t * 4];
        int s = offs[n], e = offs[n + 1];
        float4 ga = { 0.f, 0.f, 0.f, 0.f };
        for (int k = s; k < e; k++) {
            int2 ew = cpk[k];
            float w = __int_as_float(ew.y);
            float4 v = *(const float4*)&T1t[(size_t)ew.x * 96 + t * 4];
            ga.x += w * v.x; ga.y += w * v.y; ga.z += w * v.z; ga.w += w * v.w;
        }
        *(float4*)&s2[t * 4] = ga;
    }
    for (int i = t; i < 288; i += 64) sw[i] = W[i];
    if (t < 32) sb[t] = bias[t];
    __syncthreads();

    int f0 = (t & 7) * 4;
    int b0 = (t >> 3) * 4;
    float acc[4][4];
#pragma unroll
    for (int bi = 0; bi < 4; bi++)
#pragma unroll
        for (int fi = 0; fi < 4; fi++) acc[bi][fi] = sb[f0 + fi];
#pragma unroll
    for (int c = 0; c < 3; c++) {
        float4 w0 = *(float4*)&sw[(0 * 3 + c) * 32 + f0];
        float4 w1 = *(float4*)&sw[(1 * 3 + c) * 32 + f0];
        float4 w2 = *(float4*)&sw[(2 * 3 + c) * 32 + f0];
#pragma unroll
        for (int bi = 0; bi < 4; bi++) {
            int b = b0 + bi;
            float x0 = s0[b * 3 + c], x1 = s1[b * 3 + c];
            float x2 = 2.f * s2[b * 3 + c] - x0;
            acc[bi][0] += x0 * w0.x + x1 * w1.x + x2 * w2.x;
            acc[bi][1] += x0 * w0.y + x1 * w1.y + x2 * w2.y;
            acc[bi][2] += x0 * w0.z + x1 * w1.z + x2 * w2.z;
            acc[bi][3] += x0 * w0.w + x1 * w1.w + x2 * w2.w;
        }
    }
#pragma unroll
    for (int bi = 0; bi < 4; bi++) {
        float4 v = { acc[bi][0], acc[bi][1], acc[bi][2], acc[bi][3] };
        *(float4*)&Yout[(size_t)j * 1024 + (b0 + bi) * 32 + f0] = v;
    }
}

// ---------------- levels 1-4 prop: block-per-node, float4 per thread ----------------
__global__ void k_propC(const float* __restrict__ Yin, float* __restrict__ T1,
                        const int* __restrict__ offs, const int2* __restrict__ cpk) {
    int n = blockIdx.x;
    int q = threadIdx.x * 4;
    int s = offs[n], e = offs[n + 1];
    float4 acc = { 0.f, 0.f, 0.f, 0.f };
    for (int k = s; k < e; k++) {
        int2 ew = cpk[k];
        float w = __int_as_float(ew.y);
        float4 v = *(const float4*)&Yin[((size_t)ew.x << 10) + q];
        acc.x += w * v.x; acc.y += w * v.y; acc.z += w * v.z; acc.w += w * v.w;
    }
    *(float4*)&T1[((size_t)n << 10) + q] = acc;
}

// ---------------- levels 1-4 combine (64 threads) ----------------
__global__ void k_combC(const float* __restrict__ Yin, const float* __restrict__ T1,
                        const int* __restrict__ offs, const int2* __restrict__ cpk,
                        const int* __restrict__ pool,
                        const float* __restrict__ W, const float* __restrict__ bias,
                        float* __restrict__ Yout, int doTanh, int bMajor) {
    __shared__ float s0[32 * 33], s1[32 * 33], s2[32 * 33], sw[3072], sb[32];
    int t = threadIdx.x;
    int j = blockIdx.x;
    int n = pool ? pool[j] : j;
    size_t nb = (size_t)n << 10;
#pragma unroll
    for (int i = 0; i < 4; i++) {
        int q = t * 4 + i * 256;
        float4 v0 = *(const float4*)&Yin[nb + q];
        float4 v1 = *(const float4*)&T1[nb + q];
        int li = (q >> 5) * 33 + (q & 31);
        s0[li] = v0.x; s0[li + 1] = v0.y; s0[li + 2] = v0.z; s0[li + 3] = v0.w;
        s1[li] = v1.x; s1[li + 1] = v1.y; s1[li + 2] = v1.z; s1[li + 3] = v1.w;
    }
    {
        int s = offs[n], e = offs[n + 1];
        float4 ga[4];
#pragma unroll
        for (int i = 0; i < 4; i++) ga[i] = make_float4(0.f, 0.f, 0.f, 0.f);
        for (int k = s; k < e; k++) {
            int2 ew = cpk[k];
            float w = __int_as_float(ew.y);
            const float* bp = T1 + ((size_t)ew.x << 10);
#pragma unroll
            for (int i = 0; i < 4; i++) {
                float4 v = *(const float4*)&bp[t * 4 + i * 256];
                ga[i].x += w * v.x; ga[i].y += w * v.y;
                ga[i].z += w * v.z; ga[i].w += w * v.w;
            }
        }
#pragma unroll
        for (int i = 0; i < 4; i++) {
            int q = t * 4 + i * 256;
            int li = (q >> 5) * 33 + (q & 31);
            s2[li] = ga[i].x; s2[li + 1] = ga[i].y; s2[li + 2] = ga[i].z; s2[li + 3] = ga[i].w;
        }
    }
    for (int i = t; i < 768; i += 64) ((float4*)sw)[i] = ((const float4*)W)[i];
    if (t < 32) sb[t] = bias[t];
    __syncthreads();

    int f0 = (t & 7) * 4;
    int b0 = (t >> 3) * 4;
    float acc[4][4];
#pragma unroll
    for (int bi = 0; bi < 4; bi++)
#pragma unroll
        for (int fi = 0; fi < 4; fi++) acc[bi][fi] = sb[f0 + fi];
    for (int c = 0; c < 32; c++) {
        float4 w0 = *(float4*)&sw[c * 32 + f0];
        float4 w1 = *(float4*)&sw[1024 + c * 32 + f0];
        float4 w2 = *(float4*)&sw[2048 + c * 32 + f0];
#pragma unroll
        for (int bi = 0; bi < 4; bi++) {
            int li = (b0 + bi) * 33 + c;
            float x0 = s0[li], x1 = s1[li];
            float x2 = 2.f * s2[li] - x0;
            acc[bi][0] += x0 * w0.x + x1 * w1.x + x2 * w2.x;
            acc[bi][1] += x0 * w0.y + x1 * w1.y + x2 * w2.y;
            acc[bi][2] += x0 * w0.z + x1 * w1.z + x2 * w2.z;
            acc[bi][3] += x0 * w0.w + x1 * w1.w + x2 * w2.w;
        }
    }
    if (doTanh) {
#pragma unroll
        for (int bi = 0; bi < 4; bi++)
#pragma unroll
            for (int fi = 0; fi < 4; fi++) acc[bi][fi] = tanhf(acc[bi][fi]);
    }
#pragma unroll
    for (int bi = 0; bi < 4; bi++) {
        float4 v = { acc[bi][0], acc[bi][1], acc[bi][2], acc[bi][3] };
        if (bMajor)
            *(float4*)&Yout[(size_t)(b0 + bi) * FDIM + j * 32 + f0] = v;
        else
            *(float4*)&Yout[((size_t)j << 10) + (b0 + bi) * 32 + f0] = v;
    }
}

// ---------------- MLP ----------------
// Z[32][4096] @ W[4096][4096] -> Hp[kc][32][4096] partials.
// grid (16, KC=64) = 1024 blocks -> 4 blocks/CU. W loads software-pipelined.
// PROVEN round-2 version: 68 VGPR, no spill. Do not shrink tiles without
// verifying VGPR via -Rpass-analysis (R5 spill lesson).
__global__ void __launch_bounds__(256, 4) k_gemm(const float* __restrict__ Z,
                                                 const float* __restrict__ W,
                                                 float* __restrict__ Hp) {
    int t = threadIdx.x; int bx = blockIdx.x; int kc = blockIdx.y; int kb = kc * 64;
    __shared__ float zs[32][64];
    for (int i = t; i < 512; i += 256) {
        int fl = i * 4; int b = fl >> 6; int k = fl & 63;
        *(float4*)&zs[b][k] = *(const float4*)&Z[(size_t)b * 4096 + kb + k];
    }
    __syncthreads();
    int ft = t & 63, bt = t >> 6;
    int f0 = bx * 256 + ft * 4;
    int b0 = bt * 8;
    const float* Wp = W + (size_t)kb * 4096 + f0;
    float acc[8][4];
#pragma unroll
    for (int bi = 0; bi < 8; bi++)
#pragma unroll
        for (int fi = 0; fi < 4; fi++) acc[bi][fi] = 0.f;
    float4 w[4], wn[4];
#pragma unroll
    for (int j = 0; j < 4; j++)
        w[j] = *(const float4*)&Wp[(size_t)j * 4096];
    for (int k4 = 0; k4 < 16; k4++) {
        if (k4 < 15) {
#pragma unroll
            for (int j = 0; j < 4; j++)
                wn[j] = *(const float4*)&Wp[(size_t)(k4 * 4 + 4 + j) * 4096];
        }
        float4 z[8];
#pragma unroll
        for (int bi = 0; bi < 8; bi++)
            z[bi] = *(const float4*)&zs[b0 + bi][k4 * 4];
#pragma unroll
        for (int bi = 0; bi < 8; bi++) {
            acc[bi][0] += z[bi].x * w[0].x + z[bi].y * w[1].x + z[bi].z * w[2].x + z[bi].w * w[3].x;
            acc[bi][1] += z[bi].x * w[0].y + z[bi].y * w[1].y + z[bi].z * w[2].y + z[bi].w * w[3].y;
            acc[bi][2] += z[bi].x * w[0].z + z[bi].y * w[1].z + z[bi].z * w[2].z + z[bi].w * w[3].z;
            acc[bi][3] += z[bi].x * w[0].w + z[bi].y * w[1].w + z[bi].z * w[2].w + z[bi].w * w[3].w;
        }
        if (k4 < 15) {
#pragma unroll
            for (int j = 0; j < 4; j++) w[j] = wn[j];
        }
    }
    float* o = Hp + (size_t)kc * 32 * 4096;
#pragma unroll
    for (int bi = 0; bi < 8; bi++) {
        float4 v = { acc[bi][0], acc[bi][1], acc[bi][2], acc[bi][3] };
        *(float4*)&o[(size_t)(b0 + bi) * 4096 + f0] = v;
    }
}

// reduce KC partials + BN(batch) + affine + relu.
// grid 128 (32 f each), block 256 = 8 f-quads x 32 rows; float4 loads.
__global__ void k_bnrelu(const float* __restrict__ Hp, const float* __restrict__ g,
                         const float* __restrict__ be, float* __restrict__ Zo) {
    __shared__ float sv[32][33], sm[32], si[32];
    int t = threadIdx.x;
    int fq = t & 7;           // f-quad 0..7
    int row = t >> 3;         // 0..31
    int f0 = blockIdx.x * 32 + fq * 4;
    float4 v = { 0.f, 0.f, 0.f, 0.f };
    for (int p = 0; p < KC; p++) {
        float4 h = *(const float4*)&Hp[(size_t)p * 32 * 4096 + (size_t)row * 4096 + f0];
        v.x += h.x; v.y += h.y; v.z += h.z; v.w += h.w;
    }
    sv[row][fq * 4 + 0] = v.x; sv[row][fq * 4 + 1] = v.y;
    sv[row][fq * 4 + 2] = v.z; sv[row][fq * 4 + 3] = v.w;
    __syncthreads();
    if (t < 32) {
        float m = 0.f, q = 0.f;
#pragma unroll
        for (int r = 0; r < 32; r++) { float x = sv[r][t]; m += x; q += x * x; }
        m *= (1.f / 32.f);
        q = q * (1.f / 32.f) - m * m;
        sm[t] = m; si[t] = rsqrtf(fmaxf(q, 0.f) + EPSBN);
    }
    __syncthreads();
    int fl = fq * 4;
    float4 o;
    o.x = (v.x - sm[fl + 0]) * si[fl + 0] * g[f0 + 0] + be[f0 + 0];
    o.y = (v.y - sm[fl + 1]) * si[fl + 1] * g[f0 + 1] + be[f0 + 1];
    o.z = (v.z - sm[fl + 2]) * si[fl + 2] * g[f0 + 2] + be[f0 + 2];
    o.w = (v.w - sm[fl + 3]) * si[fl + 3] * g[f0 + 3] + be[f0 + 3];
    o.x = fmaxf(o.x, 0.f); o.y = fmaxf(o.y, 0.f);
    o.z = fmaxf(o.z, 0.f); o.w = fmaxf(o.w, 0.f);
    *(float4*)&Zo[(size_t)row * 4096 + f0] = o;
}

// Z[32][4096] @ W9[4096][128] -> Mp[kc][32][128]. grid KC9, block 128 = 32f(4) x 4bq(8).
__global__ void __launch_bounds__(128, 2) k_gemm9(const float* __restrict__ Z,
                                                  const float* __restrict__ W9,
                                                  float* __restrict__ Mp) {
    int t = threadIdx.x; int kc = blockIdx.x; int kb = kc * 64;
    __shared__ float zs[32][64];
    for (int i = t; i < 512; i += 128) {
        int fl = i * 4; int b = fl >> 6; int k = fl & 63;
        *(float4*)&zs[b][k] = *(const float4*)&Z[(size_t)b * 4096 + kb + k];
    }
    __syncthreads();
    int ft = t & 31, bt = t >> 5;
    int f0 = ft * 4;
    int b0 = bt * 8;
    const float* Wp = W9 + (size_t)kb * 128 + f0;
    float acc[8][4];
#pragma unroll
    for (int bi = 0; bi < 8; bi++)
#pragma unroll
        for (int fi = 0; fi < 4; fi++) acc[bi][fi] = 0.f;
    for (int k4 = 0; k4 < 16; k4++) {
        float4 w[4];
#pragma unroll
        for (int j = 0; j < 4; j++)
            w[j] = *(const float4*)&Wp[(size_t)(k4 * 4 + j) * 128];
        float4 z[8];
#pragma unroll
        for (int bi = 0; bi < 8; bi++)
            z[bi] = *(const float4*)&zs[b0 + bi][k4 * 4];
#pragma unroll
        for (int bi = 0; bi < 8; bi++) {
            acc[bi][0] += z[bi].x * w[0].x + z[bi].y * w[1].x + z[bi].z * w[2].x + z[bi].w * w[3].x;
            acc[bi][1] += z[bi].x * w[0].y + z[bi].y * w[1].y + z[bi].z * w[2].y + z[bi].w * w[3].y;
            acc[bi][2] += z[bi].x * w[0].z + z[bi].y * w[1].z + z[bi].z * w[2].z + z[bi].w * w[3].z;
            acc[bi][3] += z[bi].x * w[0].w + z[bi].y * w[1].w + z[bi].z * w[2].w + z[bi].w * w[3].w;
        }
    }
    float* o = Mp + (size_t)kc * 32 * 128;
#pragma unroll
    for (int bi = 0; bi < 8; bi++) {
        float4 v = { acc[bi][0], acc[bi][1], acc[bi][2], acc[bi][3] };
        *(float4*)&o[(b0 + bi) * 128 + f0] = v;
    }
}

// float4 reduce of gemm9 partials: 4 blocks x 256 threads cover 4096 slots.
__global__ void k_red9(const float* __restrict__ Mp, float* __restrict__ Mu) {
    int idx4 = (blockIdx.x * 256 + threadIdx.x) * 4;
    float4 a = { 0.f, 0.f, 0.f, 0.f };
    for (int p = 0; p < KC9; p++) {
        float4 m = *(const float4*)&Mp[(size_t)p * 4096 + idx4];
        a.x += m.x; a.y += m.y; a.z += m.z; a.w += m.w;
    }
    *(float4*)&Mu[idx4] = a;
}

__global__ void k_bnfinal(const float* __restrict__ Mu, float* __restrict__ out) {
    int f = threadIdx.x;
    float v[32], s = 0.f;
#pragma unroll
    for (int b = 0; b < 32; b++) { v[b] = Mu[b * 128 + f]; s += v[b]; }
    float m = s * (1.f / 32.f), q = 0.f;
#pragma unroll
    for (int b = 0; b < 32; b++) { float d = v[b] - m; q += d * d; }
    float inv = rsqrtf(q * (1.f / 32.f) + EPSBN);
#pragma unroll
    for (int b = 0; b < 32; b++) out[b * 128 + f] = (v[b] - m) * inv;
}

// ---------------- host ----------------
extern "C" void kernel_launch(void* const* d_in, const int* in_sizes, int n_in,
                              void* d_out, int out_size, void* d_ws, size_t ws_size,
                              hipStream_t stream) {
    const float* x  = (const float*)d_in[0];
    const int* e0 = (const int*)d_in[1];
    const int* e1 = (const int*)d_in[2];
    const int* e2 = (const int*)d_in[3];
    const int* e3 = (const int*)d_in[4];
    const int* l0 = (const int*)d_in[5];
    const int* l1 = (const int*)d_in[6];
    const int* l2 = (const int*)d_in[7];
    const float* Wc1 = (const float*)d_in[8];
    const float* b1  = (const float*)d_in[9];
    const float* Wc2 = (const float*)d_in[10];
    const float* b2  = (const float*)d_in[11];
    const float* Wc3 = (const float*)d_in[12];
    const float* b3  = (const float*)d_in[13];
    const float* Wc4 = (const float*)d_in[14];
    const float* b4  = (const float*)d_in[15];
    const float* Wc5 = (const float*)d_in[16];
    const float* b5  = (const float*)d_in[17];
    const float* W6  = (const float*)d_in[18];
    const float* g6  = (const float*)d_in[20];
    const float* be6 = (const float*)d_in[21];
    const float* W7  = (const float*)d_in[22];
    const float* g7  = (const float*)d_in[24];
    const float* be7 = (const float*)d_in[25];
    const float* W8  = (const float*)d_in[26];
    const float* g8  = (const float*)d_in[28];
    const float* be8 = (const float*)d_in[29];
    const float* W9  = (const float*)d_in[30];
    float* out = (float*)d_out;

    char* p = (char*)d_ws;
    size_t o = 0;
    auto carve = [&](size_t bytes) {
        void* r = (void*)(p + o);
        o += (bytes + 255) & ~(size_t)255;
        return r;
    };
    // graph-phase buffers (dead by MLP time; Hp aliases this span)
    float* xt  = (float*)carve((size_t)N0 * 96 * 4);       // 6.3 MB
    float* T1t = (float*)carve((size_t)N0 * 96 * 4);       // 6.3 MB
    float* Y1  = (float*)carve((size_t)N1 * 1024 * 4);     // 16.8 MB
    float* T1c = (float*)carve((size_t)N1 * 1024 * 4);     // 16.8 MB (reused all levels)
    float* Y2  = (float*)carve((size_t)N2 * 1024 * 4);     // 4.2 MB
    float* Y3  = (float*)carve((size_t)N3 * 1024 * 4);     // 0.5 MB
    float* Y4  = (float*)carve((size_t)N3 * 1024 * 4);     // 0.5 MB
    float* Zb0 = (float*)carve((size_t)BB * FDIM * 4);
    float* Zb1 = (float*)carve((size_t)BB * FDIM * 4);
    float* Mp  = (float*)carve((size_t)KC9 * BB * LDIM * 4);
    float* Mu  = (float*)carve((size_t)BB * LDIM * 4);
    int* deg  = (int*)carve(NT * sizeof(int));
    int* offs = (int*)carve((NT + 1) * sizeof(int));
    int* cur  = (int*)carve(NT * sizeof(int));
    int2* cpk = (int2*)carve(ET * sizeof(int2));
    float* Hp = xt;  // alias: KC*32*4096*4 = 33.6 MB fits in xt..T1c span (46.2 MB)
    (void)ws_size;

    // CSR for all 4 levels
    hipMemsetAsync(deg, 0, NT * sizeof(int), stream);
    k_count<<<(ET + 255) / 256, 256, 0, stream>>>(e0, e1, e2, e3, deg);
    k_scan<<<1, 1024, 0, stream>>>(deg, offs, cur);
    k_scatter<<<(ET + 255) / 256, 256, 0, stream>>>(e0, e1, e2, e3, deg, cur, cpk);

    const int* off0 = offs;
    const int* off1 = offs + N0;
    const int* off2 = offs + N0 + N1;
    const int* off3 = offs + N0 + N1 + N2;

    // node-major transpose of x
    k_transpose<<<N0 / 32, dim3(32, 8), 0, stream>>>(x, xt);

    // level 0
    k_prop0<<<(N0 * 24) / 256, 256, 0, stream>>>(xt, T1t, off0, cpk);
    k_comb0<<<N1, 64, 0, stream>>>(xt, T1t, off0, cpk, l0, Wc1, b1, Y1);
    // level 1
    k_propC<<<N1, 256, 0, stream>>>(Y1, T1c, off1, cpk);
    k_combC<<<N2, 64, 0, stream>>>(Y1, T1c, off1, cpk, l1, Wc2, b2, Y2, 1, 0);
    // level 2
    k_propC<<<N2, 256, 0, stream>>>(Y2, T1c, off2, cpk);
    k_combC<<<N3, 64, 0, stream>>>(Y2, T1c, off2, cpk, l2, Wc3, b3, Y3, 1, 0);
    // level 3
    k_propC<<<N3, 256, 0, stream>>>(Y3, T1c, off3, cpk);
    k_combC<<<N3, 64, 0, stream>>>(Y3, T1c, off3, cpk, nullptr, Wc4, b4, Y4, 1, 0);
    // level 4 -> batch-major Z
    k_propC<<<N3, 256, 0, stream>>>(Y4, T1c, off3, cpk);
    k_combC<<<N3, 64, 0, stream>>>(Y4, T1c, off3, cpk, nullptr, Wc5, b5, Zb0, 0, 1);

    // MLP (Hp aliases graph buffers — graph section fully precedes this)
    const float* Ws[3]  = { W6, W7, W8 };
    const float* gs[3]  = { g6, g7, g8 };
    const float* bes[3] = { be6, be7, be8 };
    float* zin = Zb0; float* zout = Zb1;
    for (int l = 0; l < 3; l++) {
        k_gemm<<<dim3(16, KC), 256, 0, stream>>>(zin, Ws[l], Hp);
        k_bnrelu<<<128, 256, 0, stream>>>(Hp, gs[l], bes[l], zout);
        float* tmp = zin; zin = zout; zout = tmp;
    }
    k_gemm9<<<KC9, 128, 0, stream>>>(zin, W9, Mp);
    k_red9<<<4, 256, 0, stream>>>(Mp, Mu);
    k_bnfinal<<<1, 128, 0, stream>>>(Mu, out);
    (void)out_size; (void)n_in; (void)in_sizes;
}